// Round 3
// baseline (1093.177 us; speedup 1.0000x reference)
//
#include <hip/hip_runtime.h>
#include <cmath>

#define EPS_BN 1e-5f
#define EPS_SM 1e-16f

typedef _Float16 f16x8 __attribute__((ext_vector_type(8)));
typedef _Float16 f16x4 __attribute__((ext_vector_type(4)));
typedef float f32x4 __attribute__((ext_vector_type(4)));
union F4 { float4 v; float a[4]; };

// ============================ utility: zero fill ============================
__global__ void zero_kernel(int* __restrict__ p, int n) {
    int i = blockIdx.x * 256 + threadIdx.x;
    if (i < n) p[i] = 0;
}

// ============================ CSR build ============================
__global__ void hist_kernel(const int* __restrict__ edst, int* __restrict__ deg, int E) {
    int e = blockIdx.x * 256 + threadIdx.x;
    if (e < E) atomicAdd(&deg[edst[e]], 1);
}

__global__ void scan1_kernel(const int* __restrict__ deg, int* __restrict__ row_ptr,
                             int* __restrict__ bsum, int N) {
    __shared__ int s[256];
    int t = threadIdx.x;
    int i = blockIdx.x * 256 + t;
    int v = (i < N) ? deg[i] : 0;
    s[t] = v; __syncthreads();
    for (int off = 1; off < 256; off <<= 1) {
        int x = (t >= off) ? s[t - off] : 0;
        __syncthreads();
        s[t] += x;
        __syncthreads();
    }
    if (i < N) row_ptr[i] = s[t] - v;   // exclusive partial
    if (t == 255) bsum[blockIdx.x] = s[t];
}

__global__ void scan2_kernel(int* __restrict__ bsum, int nb) {
    __shared__ int s[1024];
    int t = threadIdx.x;
    int v = (t < nb) ? bsum[t] : 0;
    s[t] = v; __syncthreads();
    for (int off = 1; off < 1024; off <<= 1) {
        int x = (t >= off) ? s[t - off] : 0;
        __syncthreads();
        s[t] += x;
        __syncthreads();
    }
    if (t < nb) bsum[t] = s[t] - v;     // exclusive
}

__global__ void scan3_kernel(int* __restrict__ row_ptr, int* __restrict__ cursor,
                             const int* __restrict__ bsum, int N, int E) {
    int i = blockIdx.x * 256 + threadIdx.x;
    if (i < N) {
        int v = row_ptr[i] + bsum[blockIdx.x];
        row_ptr[i] = v;
        cursor[i] = v;
    } else if (i == N) {
        row_ptr[N] = E;
    }
}

// writes pos[e] = CSR slot of edge e (dst-grouped)
__global__ void scatter_kernel(const int* __restrict__ edst, int* __restrict__ cursor,
                               int* __restrict__ pos, int E) {
    int e = blockIdx.x * 256 + threadIdx.x;
    if (e < E) {
        int p = atomicAdd(&cursor[edst[e]], 1);
        pos[e] = p;
    }
}

// graph ranges by binary search (batch is sorted)
__global__ void gptr_kernel(const int* __restrict__ batch, int* __restrict__ gptr, int N, int G) {
    int g = blockIdx.x * 256 + threadIdx.x;
    if (g > G) return;
    int lo = 0, hi = N;
    while (lo < hi) { int mid = (lo + hi) >> 1; if (batch[mid] < g) lo = mid + 1; else hi = mid; }
    gptr[g] = lo;
}

// ============================ input projection ============================
__global__ void proj_kernel(const float* __restrict__ x, const float* __restrict__ lin_w,
                            const float* __restrict__ lin_b, float* __restrict__ h, int N) {
    __shared__ float Xs[64 * 32];
    int t = threadIdx.x;
    int col = t & 63, sub = t >> 6;
    float w[32];
#pragma unroll
    for (int k = 0; k < 32; k++) w[k] = lin_w[k * 64 + col];
    float b = lin_b[col];
    int r0 = blockIdx.x * 64;
    const float4* xg = (const float4*)(x + (size_t)r0 * 32);
    float4* Xs4 = (float4*)Xs;
    size_t totf4 = (size_t)N * 8;
#pragma unroll
    for (int i = 0; i < 2; i++) {
        int idx = t + i * 256;
        size_t gidx = (size_t)r0 * 8 + idx;
        Xs4[idx] = (gidx < totf4) ? xg[idx] : make_float4(0.f, 0.f, 0.f, 0.f);
    }
    __syncthreads();
    for (int rr = sub; rr < 64; rr += 4) {
        int r = r0 + rr;
        if (r >= N) break;
        float acc = b;
        const float4* a4p = (const float4*)(Xs + rr * 32);
#pragma unroll
        for (int kk = 0; kk < 8; kk++) {
            float4 a4 = a4p[kk];
            acc += a4.x * w[kk * 4] + a4.y * w[kk * 4 + 1] + a4.z * w[kk * 4 + 2] + a4.w * w[kk * 4 + 3];
        }
        h[(size_t)r * 64 + col] = fmaxf(acc, 0.f);
    }
}

// ============================ BN stats (per-block partials) ============================
__global__ void bn_stats_kernel(const float* __restrict__ h, float* __restrict__ bnpart, int N) {
    __shared__ float ls[256], lq[256];
    int t = threadIdx.x, c = t & 63, sub = t >> 6;
    int r0 = blockIdx.x * 512;
    int rend = min(r0 + 512, N);
    float s = 0.f, q = 0.f;
    for (int r = r0 + sub; r < rend; r += 4) {
        float v = h[(size_t)r * 64 + c];
        s += v; q += v * v;
    }
    ls[t] = s; lq[t] = q;
    __syncthreads();
    if (t < 64) {
        float S = ls[t] + ls[t + 64] + ls[t + 128] + ls[t + 192];
        float Qv = lq[t] + lq[t + 64] + lq[t + 128] + lq[t + 192];
        bnpart[(size_t)blockIdx.x * 128 + t] = S;
        bnpart[(size_t)blockIdx.x * 128 + 64 + t] = Qv;
    }
}

// ============================ fold BN + attention vectors into weights ============================
// Wp[64,256]=scl[k]*W[k,j]; bpb[256]=sum_k sft[k]*W[k,j]
// P[64,8], cs[8] : logit projections (src 0-3, dst 4-7)
// Qm[8,4] : edge-attr logit fold
// Wt[64,256] f16: Wt[col][c*4+h] = 0.25*Wp[c][h*64+col]  (B matrix for MFMA, k=c*4+h)
__global__ void fold_kernel(const float* __restrict__ bnpart, int nb,
                            const float* __restrict__ gamma, const float* __restrict__ beta,
                            const float* __restrict__ convw, const float* __restrict__ convwe,
                            const float* __restrict__ atts, const float* __restrict__ attd,
                            const float* __restrict__ atte,
                            float* __restrict__ Wp, float* __restrict__ bpb,
                            float* __restrict__ P, float* __restrict__ cs, float* __restrict__ Qm,
                            _Float16* __restrict__ Wt,
                            float invN) {
    __shared__ float scl[64], sft[64], red[128];
    int t = threadIdx.x;
    if (t < 128) {
        float s = 0.f;
        for (int b = 0; b < nb; b++) s += bnpart[(size_t)b * 128 + t];
        red[t] = s;
    }
    __syncthreads();
    if (t < 64) {
        float mu = red[t] * invN;
        float var = red[64 + t] * invN - mu * mu;
        var = fmaxf(var, 0.f);
        float sc = gamma[t] / sqrtf(var + EPS_BN);
        scl[t] = sc;
        sft[t] = beta[t] - mu * sc;
    }
    __syncthreads();
    {
        float bacc = 0.f;
        for (int k = 0; k < 64; k++) {
            float wv = convw[k * 256 + t];
            Wp[k * 256 + t] = scl[k] * wv;
            bacc += sft[k] * wv;
        }
        bpb[t] = bacc;
    }
    __syncthreads();
    for (int idx = t; idx < 512; idx += 256) {
        int k = idx >> 3, o = idx & 7, hh = o & 3;
        const float* av = (o < 4) ? atts : attd;
        float acc = 0.f;
        for (int c = 0; c < 64; c++) acc += Wp[k * 256 + hh * 64 + c] * av[hh * 64 + c];
        P[idx] = acc;
    }
    for (int idx = t; idx < 16384; idx += 256) {
        int col = idx >> 8, k = idx & 255;
        int c = k >> 2, hh = k & 3;
        Wt[idx] = (_Float16)(Wp[c * 256 + hh * 64 + col] * 0.25f);
    }
    if (t < 8) {
        int hh = t & 3;
        const float* av = (t < 4) ? atts : attd;
        float acc = 0.f;
        for (int c = 0; c < 64; c++) acc += bpb[hh * 64 + c] * av[hh * 64 + c];
        cs[t] = acc;
    }
    if (t < 32) {
        int f = t >> 2, hh = t & 3;
        float acc = 0.f;
        for (int c = 0; c < 64; c++) acc += convwe[f * 256 + hh * 64 + c] * atte[hh * 64 + c];
        Qm[t] = acc;
    }
}

// ============================ per-node attention logits: a_sd = h @ P + cs ============================
__global__ void att_node_kernel(const float* __restrict__ h, const float* __restrict__ P,
                                const float* __restrict__ cs, float* __restrict__ a_sd, int N) {
    __shared__ float As[32 * 64];
    __shared__ float Ps[512];
    __shared__ float css[8];
    int t = threadIdx.x;
    int r0 = blockIdx.x * 32;
    const float4* hg = (const float4*)(h + (size_t)r0 * 64);
    float4* As4 = (float4*)As;
    size_t totf4 = (size_t)N * 16;
#pragma unroll
    for (int i = 0; i < 2; i++) {
        int idx = t + i * 256;
        size_t gidx = (size_t)r0 * 16 + idx;
        As4[idx] = (gidx < totf4) ? hg[idx] : make_float4(0.f, 0.f, 0.f, 0.f);
    }
    Ps[t] = P[t];
    Ps[t + 256] = P[t + 256];
    if (t < 8) css[t] = cs[t];
    __syncthreads();
    int row = t >> 3, o = t & 7;
    int rg = r0 + row;
    if (rg >= N) return;
    float acc = css[o];
#pragma unroll 8
    for (int k = 0; k < 64; k++) acc += As[row * 64 + k] * Ps[k * 8 + o];
    a_sd[(size_t)rg * 8 + o] = acc;
}

// ============================ edge exp scores, scattered to CSR order ============================
// ex = exp(leaky_relu(a_s[src] + a_d[dst] + edge_attr@Qm))  (no max subtraction: |s| << 88)
__global__ void edge_ex_kernel(const int* __restrict__ esrc, const int* __restrict__ edst,
                               const float* __restrict__ edge_attr, const float* __restrict__ a_sd,
                               const float* __restrict__ Qm, const int* __restrict__ pos,
                               float4* __restrict__ ex_csr, int* __restrict__ src_csr, int E) {
    int e = blockIdx.x * 256 + threadIdx.x;
    if (e >= E) return;
    int src = esrc[e], dst = edst[e];
    F4 ea0, ea1, as, ad;
    ea0.v = ((const float4*)edge_attr)[(size_t)e * 2];
    ea1.v = ((const float4*)edge_attr)[(size_t)e * 2 + 1];
    as.v = ((const float4*)a_sd)[(size_t)src * 2];
    ad.v = ((const float4*)a_sd)[(size_t)dst * 2 + 1];
    F4 exv;
#pragma unroll
    for (int hh = 0; hh < 4; hh++) {
        float ae = ea0.a[0] * Qm[0 * 4 + hh] + ea0.a[1] * Qm[1 * 4 + hh]
                 + ea0.a[2] * Qm[2 * 4 + hh] + ea0.a[3] * Qm[3 * 4 + hh]
                 + ea1.a[0] * Qm[4 * 4 + hh] + ea1.a[1] * Qm[5 * 4 + hh]
                 + ea1.a[2] * Qm[6 * 4 + hh] + ea1.a[3] * Qm[7 * 4 + hh];
        float s = as.a[hh] + ad.a[hh] + ae;
        s = s > 0.f ? s : 0.2f * s;
        exv.a[hh] = __expf(s);
    }
    int p = pos[e];
    ex_csr[p] = exv.v;
    src_csr[p] = src;
}

// ============================ fused aggregation + projection (MFMA) ============================
// 16 nodes per batch, 4 waves: edge phase gathers h[src] with CSR-ordered ex weights
// (no shuffles: ex/src loads are wave-uniform broadcasts, den accumulates redundantly per lane),
// writes fp16 agg rows to LDS; MFMA phase projects [16x256]@[256x64] with wave wv owning cols wv*16..+15.
__global__ __launch_bounds__(256) void msg_proj_kernel(
        const int* __restrict__ row_ptr, const int* __restrict__ src_csr,
        const float4* __restrict__ ex_csr, const float* __restrict__ h_in,
        const _Float16* __restrict__ Wt, const float* __restrict__ bpb,
        const float* __restrict__ bias, float* __restrict__ h_out, int N) {
    __shared__ __attribute__((aligned(16))) _Float16 Aagg[16][264];
    __shared__ float sals[16][4];
    int t = threadIdx.x;
    int wv = t >> 6, lane = t & 63;
    int col_in = lane & 15;
    int kb = (lane >> 4) * 8;
    int colg = wv * 16 + col_in;

    // B fragments: B[k][n], lane holds n=lane&15, k = ks*32 + (lane>>4)*8 + j
    f16x8 bfrag[8];
    const _Float16* wtp = Wt + (size_t)colg * 256 + kb;
#pragma unroll
    for (int ks = 0; ks < 8; ks++) bfrag[ks] = *(const f16x8*)(wtp + ks * 32);
    float bpbc[4];
#pragma unroll
    for (int hh = 0; hh < 4; hh++) bpbc[hh] = bpb[hh * 64 + colg] * 0.25f;
    float bcol = bias[colg];

    for (int nb = blockIdx.x * 16; nb < N; nb += gridDim.x * 16) {
        // -------- edge phase: wave wv handles nodes nb+wv*4 .. +3 --------
        for (int q = 0; q < 4; q++) {
            int row = wv * 4 + q;
            int n = nb + row;
            float A0 = 0.f, A1 = 0.f, A2 = 0.f, A3 = 0.f;
            float d0 = 0.f, d1 = 0.f, d2 = 0.f, d3 = 0.f;
            if (n < N) {
                int p0 = row_ptr[n], p1 = row_ptr[n + 1];
                for (int p = p0; p < p1; p++) {
                    int src = src_csr[p];
                    float4 ex = ex_csr[p];
                    float hv = h_in[(size_t)src * 64 + lane];
                    A0 = fmaf(ex.x, hv, A0); d0 += ex.x;
                    A1 = fmaf(ex.y, hv, A1); d1 += ex.y;
                    A2 = fmaf(ex.z, hv, A2); d2 += ex.z;
                    A3 = fmaf(ex.w, hv, A3); d3 += ex.w;
                }
            }
            float i0 = 1.f / (d0 + EPS_SM), i1 = 1.f / (d1 + EPS_SM);
            float i2 = 1.f / (d2 + EPS_SM), i3 = 1.f / (d3 + EPS_SM);
            f16x4 av;
            av.x = (_Float16)(A0 * i0);
            av.y = (_Float16)(A1 * i1);
            av.z = (_Float16)(A2 * i2);
            av.w = (_Float16)(A3 * i3);
            *(f16x4*)&Aagg[row][lane * 4] = av;
            if (lane == 0) {
                sals[row][0] = d0 / (d0 + EPS_SM);
                sals[row][1] = d1 / (d1 + EPS_SM);
                sals[row][2] = d2 / (d2 + EPS_SM);
                sals[row][3] = d3 / (d3 + EPS_SM);
            }
        }
        __syncthreads();
        // -------- MFMA phase: project 16x256 @ 256x64, wave wv -> cols wv*16..+15 --------
        f32x4 acc = {0.f, 0.f, 0.f, 0.f};
        const _Float16* ap = &Aagg[lane & 15][kb];
#pragma unroll
        for (int ks = 0; ks < 8; ks++) {
            f16x8 af = *(const f16x8*)(ap + ks * 32);
            acc = __builtin_amdgcn_mfma_f32_16x16x32_f16(af, bfrag[ks], acc, 0, 0, 0);
        }
        // epilogue: D row=(lane>>4)*4+reg, col=colg
        int r0 = (lane >> 4) * 4;
#pragma unroll
        for (int reg = 0; reg < 4; reg++) {
            int row = r0 + reg;
            int n = nb + row;
            if (n < N) {
                float v = acc[reg] + sals[row][0] * bpbc[0] + sals[row][1] * bpbc[1]
                        + sals[row][2] * bpbc[2] + sals[row][3] * bpbc[3] + bcol;
                size_t idx = (size_t)n * 64 + colg;
                float hv = h_in[idx];
                h_out[idx] = fmaxf(v, 0.f) + hv;
            }
        }
        __syncthreads();
    }
}

// ============================ pooling + FC head ============================
__global__ void pool_fc_kernel(const float* __restrict__ h, const int* __restrict__ gptr,
                               const float* __restrict__ fc1_w, const float* __restrict__ fc1_b,
                               const float* __restrict__ fc2_w, const float* __restrict__ fc2_b,
                               float* __restrict__ out, int G) {
    __shared__ float pool[4][64];
    int lane = threadIdx.x & 63, wv = threadIdx.x >> 6;
    int g = blockIdx.x * 4 + wv;
    float acc = 0.f;
    if (g < G) {
        int a = gptr[g], b = gptr[g + 1];
        for (int r = a; r < b; r++) acc += h[(size_t)r * 64 + lane];
    }
    pool[wv][lane] = acc;
    __syncthreads();
    float z1 = fc1_b[lane];
#pragma unroll 8
    for (int c = 0; c < 64; c++) z1 += pool[wv][c] * fc1_w[c * 64 + lane];
    z1 = fmaxf(z1, 0.f);
    float z2 = z1 * fc2_w[lane];
    z2 += __shfl_xor(z2, 1);
    z2 += __shfl_xor(z2, 2);
    z2 += __shfl_xor(z2, 4);
    z2 += __shfl_xor(z2, 8);
    z2 += __shfl_xor(z2, 16);
    z2 += __shfl_xor(z2, 32);
    if (g < G && lane == 0) out[g] = fmaxf(z2 + fc2_b[0], 0.f);
}

// ============================ host ============================
extern "C" void kernel_launch(void* const* d_in, const int* in_sizes, int n_in,
                              void* d_out, int out_size, void* d_ws, size_t ws_size,
                              hipStream_t stream) {
    const float* x         = (const float*)d_in[0];
    const int*   eindex    = (const int*)d_in[1];
    const float* edge_attr = (const float*)d_in[2];
    const int*   batch     = (const int*)d_in[3];
    const float* lin_w     = (const float*)d_in[4];
    const float* lin_b     = (const float*)d_in[5];
    const float* bn_gamma  = (const float*)d_in[6];
    const float* bn_beta   = (const float*)d_in[7];
    const float* conv_w    = (const float*)d_in[8];
    const float* conv_we   = (const float*)d_in[9];
    const float* att_src   = (const float*)d_in[10];
    const float* att_dst   = (const float*)d_in[11];
    const float* att_edge  = (const float*)d_in[12];
    const float* conv_bias = (const float*)d_in[13];
    const float* fc1_w     = (const float*)d_in[14];
    const float* fc1_b     = (const float*)d_in[15];
    const float* fc2_w     = (const float*)d_in[16];
    const float* fc2_b     = (const float*)d_in[17];
    float* out = (float*)d_out;

    int N = in_sizes[3];
    int E = in_sizes[1] / 2;
    int G = out_size;
    const int* esrc = eindex;
    const int* edst = eindex + E;

    char* wp = (char*)d_ws;
    auto carve = [&](size_t b) -> char* {
        char* p = wp;
        wp += (b + 511) & ~(size_t)511;
        return p;
    };
    float*     hb0    = (float*)carve((size_t)N * 64 * 4);      // 51.2 MB
    float*     hb1    = (float*)carve((size_t)N * 64 * 4);      // 51.2 MB
    float*     a_sd   = (float*)carve((size_t)N * 8 * 4);       //  6.4 MB
    float4*    ex_csr = (float4*)carve((size_t)E * 16);         //  6.4 MB
    int*       src_csr= (int*)carve((size_t)E * 4);             //  1.6 MB
    int*       deg    = (int*)carve((size_t)N * 4);
    int*       row_ptr= (int*)carve((size_t)(N + 1) * 4);
    int*       cursor = (int*)carve((size_t)N * 4);
    int*       bsum   = (int*)carve(4096);
    int*       pos    = (int*)carve((size_t)E * 4);
    int*       gptr   = (int*)carve((size_t)(G + 1) * 4);
    float*     Wp     = (float*)carve(64 * 256 * 4);
    float*     bpb    = (float*)carve(256 * 4);
    float*     P      = (float*)carve(512 * 4);
    float*     cs     = (float*)carve(8 * 4);
    float*     Qm     = (float*)carve(32 * 4);
    _Float16*  Wt     = (_Float16*)carve(64 * 256 * 2);
    int nbS = (N + 511) / 512;
    float*     bnpart = (float*)carve((size_t)nbS * 128 * 4);

    int nb1 = (N + 255) / 256;

    // CSR + graph ranges (static across layers)
    zero_kernel<<<nb1, 256, 0, stream>>>(deg, N);
    hist_kernel<<<(E + 255) / 256, 256, 0, stream>>>(edst, deg, E);
    scan1_kernel<<<nb1, 256, 0, stream>>>(deg, row_ptr, bsum, N);
    scan2_kernel<<<1, 1024, 0, stream>>>(bsum, nb1);
    scan3_kernel<<<(N + 1 + 255) / 256, 256, 0, stream>>>(row_ptr, cursor, bsum, N, E);
    scatter_kernel<<<(E + 255) / 256, 256, 0, stream>>>(edst, cursor, pos, E);
    gptr_kernel<<<(G + 1 + 255) / 256, 256, 0, stream>>>(batch, gptr, N, G);

    // input projection
    proj_kernel<<<(N + 63) / 64, 256, 0, stream>>>(x, lin_w, lin_b, hb0, N);

    int cur = 0;
    float* hbuf[2] = {hb0, hb1};
    int mpGrid = (N + 15) / 16;
    if (mpGrid > 4096) mpGrid = 4096;

    for (int l = 0; l < 3; l++) {
        float* hc = hbuf[cur];
        float* hn = hbuf[cur ^ 1];
        bn_stats_kernel<<<nbS, 256, 0, stream>>>(hc, bnpart, N);
        fold_kernel<<<1, 256, 0, stream>>>(bnpart, nbS,
                                           bn_gamma + l * 64, bn_beta + l * 64,
                                           conv_w + (size_t)l * 64 * 256,
                                           conv_we + (size_t)l * 8 * 256,
                                           att_src + l * 256, att_dst + l * 256, att_edge + l * 256,
                                           Wp, bpb, P, cs, Qm, Wt, 1.f / (float)N);
        att_node_kernel<<<(N + 31) / 32, 256, 0, stream>>>(hc, P, cs, a_sd, N);
        edge_ex_kernel<<<(E + 255) / 256, 256, 0, stream>>>(esrc, edst, edge_attr, a_sd, Qm,
                                                            pos, ex_csr, src_csr, E);
        msg_proj_kernel<<<mpGrid, 256, 0, stream>>>(row_ptr, src_csr, ex_csr, hc, Wt, bpb,
                                                    conv_bias + l * 64, hn, N);
        cur ^= 1;
    }

    pool_fc_kernel<<<(G + 3) / 4, 256, 0, stream>>>(hbuf[cur], gptr, fc1_w, fc1_b, fc2_w, fc2_b,
                                                    out, G);
}

// Round 4
// 705.159 us; speedup vs baseline: 1.5503x; 1.5503x over previous
//
#include <hip/hip_runtime.h>
#include <cmath>

#define EPS_BN 1e-5f
#define EPS_SM 1e-16f

typedef _Float16 f16x8 __attribute__((ext_vector_type(8)));
typedef _Float16 f16x4 __attribute__((ext_vector_type(4)));
typedef float f32x4 __attribute__((ext_vector_type(4)));
union F4 { float4 v; float a[4]; };

// ============================ utility: zero fill ============================
__global__ void zero_kernel(int* __restrict__ p, int n) {
    int i = blockIdx.x * 256 + threadIdx.x;
    if (i < n) p[i] = 0;
}

// ============================ CSR build ============================
__global__ void hist_kernel(const int* __restrict__ edst, int* __restrict__ deg, int E) {
    int e = blockIdx.x * 256 + threadIdx.x;
    if (e < E) atomicAdd(&deg[edst[e]], 1);
}

__global__ void scan1_kernel(const int* __restrict__ deg, int* __restrict__ row_ptr,
                             int* __restrict__ bsum, int N) {
    __shared__ int s[256];
    int t = threadIdx.x;
    int i = blockIdx.x * 256 + t;
    int v = (i < N) ? deg[i] : 0;
    s[t] = v; __syncthreads();
    for (int off = 1; off < 256; off <<= 1) {
        int x = (t >= off) ? s[t - off] : 0;
        __syncthreads();
        s[t] += x;
        __syncthreads();
    }
    if (i < N) row_ptr[i] = s[t] - v;   // exclusive partial
    if (t == 255) bsum[blockIdx.x] = s[t];
}

__global__ void scan2_kernel(int* __restrict__ bsum, int nb) {
    __shared__ int s[1024];
    int t = threadIdx.x;
    int v = (t < nb) ? bsum[t] : 0;
    s[t] = v; __syncthreads();
    for (int off = 1; off < 1024; off <<= 1) {
        int x = (t >= off) ? s[t - off] : 0;
        __syncthreads();
        s[t] += x;
        __syncthreads();
    }
    if (t < nb) bsum[t] = s[t] - v;     // exclusive
}

__global__ void scan3_kernel(int* __restrict__ row_ptr, int* __restrict__ cursor,
                             const int* __restrict__ bsum, int N, int E) {
    int i = blockIdx.x * 256 + threadIdx.x;
    if (i < N) {
        int v = row_ptr[i] + bsum[blockIdx.x];
        row_ptr[i] = v;
        cursor[i] = v;
    } else if (i == N) {
        row_ptr[N] = E;
    }
}

// writes pos[e] = CSR slot of edge e (dst-grouped)
__global__ void scatter_kernel(const int* __restrict__ edst, int* __restrict__ cursor,
                               int* __restrict__ pos, int E) {
    int e = blockIdx.x * 256 + threadIdx.x;
    if (e < E) {
        int p = atomicAdd(&cursor[edst[e]], 1);
        pos[e] = p;
    }
}

// graph ranges by binary search (batch is sorted)
__global__ void gptr_kernel(const int* __restrict__ batch, int* __restrict__ gptr, int N, int G) {
    int g = blockIdx.x * 256 + threadIdx.x;
    if (g > G) return;
    int lo = 0, hi = N;
    while (lo < hi) { int mid = (lo + hi) >> 1; if (batch[mid] < g) lo = mid + 1; else hi = mid; }
    gptr[g] = lo;
}

// ============================ input projection ============================
__global__ void proj_kernel(const float* __restrict__ x, const float* __restrict__ lin_w,
                            const float* __restrict__ lin_b, float* __restrict__ h, int N) {
    __shared__ float Xs[64 * 32];
    int t = threadIdx.x;
    int col = t & 63, sub = t >> 6;
    float w[32];
#pragma unroll
    for (int k = 0; k < 32; k++) w[k] = lin_w[k * 64 + col];
    float b = lin_b[col];
    int r0 = blockIdx.x * 64;
    const float4* xg = (const float4*)(x + (size_t)r0 * 32);
    float4* Xs4 = (float4*)Xs;
    size_t totf4 = (size_t)N * 8;
#pragma unroll
    for (int i = 0; i < 2; i++) {
        int idx = t + i * 256;
        size_t gidx = (size_t)r0 * 8 + idx;
        Xs4[idx] = (gidx < totf4) ? xg[idx] : make_float4(0.f, 0.f, 0.f, 0.f);
    }
    __syncthreads();
    for (int rr = sub; rr < 64; rr += 4) {
        int r = r0 + rr;
        if (r >= N) break;
        float acc = b;
        const float4* a4p = (const float4*)(Xs + rr * 32);
#pragma unroll
        for (int kk = 0; kk < 8; kk++) {
            float4 a4 = a4p[kk];
            acc += a4.x * w[kk * 4] + a4.y * w[kk * 4 + 1] + a4.z * w[kk * 4 + 2] + a4.w * w[kk * 4 + 3];
        }
        h[(size_t)r * 64 + col] = fmaxf(acc, 0.f);
    }
}

// ============================ BN stats (per-block partials) ============================
__global__ void bn_stats_kernel(const float* __restrict__ h, float* __restrict__ bnpart, int N) {
    __shared__ float ls[256], lq[256];
    int t = threadIdx.x, c = t & 63, sub = t >> 6;
    int r0 = blockIdx.x * 512;
    int rend = min(r0 + 512, N);
    float s = 0.f, q = 0.f;
    for (int r = r0 + sub; r < rend; r += 4) {
        float v = h[(size_t)r * 64 + c];
        s += v; q += v * v;
    }
    ls[t] = s; lq[t] = q;
    __syncthreads();
    if (t < 64) {
        float S = ls[t] + ls[t + 64] + ls[t + 128] + ls[t + 192];
        float Qv = lq[t] + lq[t + 64] + lq[t + 128] + lq[t + 192];
        bnpart[(size_t)blockIdx.x * 128 + t] = S;
        bnpart[(size_t)blockIdx.x * 128 + 64 + t] = Qv;
    }
}

// reduce bnpart over blocks: red[stat] = sum_b bnpart[b][stat], stat = blockIdx (128 blocks)
__global__ void bn_reduce_kernel(const float* __restrict__ bnpart, int nb, float* __restrict__ red) {
    __shared__ float s[256];
    int stat = blockIdx.x;
    float acc = 0.f;
    for (int j = threadIdx.x; j < nb; j += 256) acc += bnpart[(size_t)j * 128 + stat];
    s[threadIdx.x] = acc;
    __syncthreads();
    for (int off = 128; off >= 1; off >>= 1) {
        if (threadIdx.x < off) s[threadIdx.x] += s[threadIdx.x + off];
        __syncthreads();
    }
    if (threadIdx.x == 0) red[stat] = s[0];
}

// ============================ fold (parallel) ============================
// blocks 0..63 : Wt[col=b][k=t] = 0.25*scl[k>>2]*convw[(k>>2)*256 + (k&3)*64 + col]
// block 64     : P[k*8+o] = scl[k]*dot(convw[k][hh*64..], att{s|d}[hh])
// block 65     : bpb[t] = sum_k sft[k]*convw[k][t];  then cs[8]
// block 66     : Qm[f*4+hh] = dot(convwe[f][hh*64..], atte[hh])
__global__ void fold2_kernel(const float* __restrict__ red,
                             const float* __restrict__ gamma, const float* __restrict__ beta,
                             const float* __restrict__ convw, const float* __restrict__ convwe,
                             const float* __restrict__ atts, const float* __restrict__ attd,
                             const float* __restrict__ atte,
                             _Float16* __restrict__ Wt, float* __restrict__ bpb,
                             float* __restrict__ P, float* __restrict__ cs, float* __restrict__ Qm,
                             float invN) {
    __shared__ float scl[64], sft[64], bs[256];
    int t = threadIdx.x;
    if (t < 64) {
        float mu = red[t] * invN;
        float var = fmaxf(red[64 + t] * invN - mu * mu, 0.f);
        float sc = gamma[t] / sqrtf(var + EPS_BN);
        scl[t] = sc;
        sft[t] = beta[t] - mu * sc;
    }
    __syncthreads();
    int b = blockIdx.x;
    if (b < 64) {
        int col = b;
        int c = t >> 2, hh = t & 3;
        Wt[col * 256 + t] = (_Float16)(0.25f * scl[c] * convw[c * 256 + hh * 64 + col]);
    } else if (b == 64) {
        for (int idx = t; idx < 512; idx += 256) {
            int k = idx >> 3, o = idx & 7, hh = o & 3;
            const float* av = (o < 4) ? atts : attd;
            float acc = 0.f;
            for (int c2 = 0; c2 < 64; c2++) acc += convw[k * 256 + hh * 64 + c2] * av[hh * 64 + c2];
            P[idx] = scl[k] * acc;
        }
    } else if (b == 65) {
        float bacc = 0.f;
        for (int k = 0; k < 64; k++) bacc += sft[k] * convw[k * 256 + t];
        bpb[t] = bacc;
        bs[t] = bacc;
        __syncthreads();
        if (t < 8) {
            int hh = t & 3;
            const float* av = (t < 4) ? atts : attd;
            float acc = 0.f;
            for (int c2 = 0; c2 < 64; c2++) acc += bs[hh * 64 + c2] * av[hh * 64 + c2];
            cs[t] = acc;
        }
    } else {
        if (t < 32) {
            int f = t >> 2, hh = t & 3;
            float acc = 0.f;
            for (int c2 = 0; c2 < 64; c2++) acc += convwe[f * 256 + hh * 64 + c2] * atte[hh * 64 + c2];
            Qm[t] = acc;
        }
    }
}

// ============================ per-node attention logits: a_sd = h @ P + cs ============================
__global__ void att_node_kernel(const float* __restrict__ h, const float* __restrict__ P,
                                const float* __restrict__ cs, float* __restrict__ a_sd, int N) {
    __shared__ float As[32 * 68];    // row stride 68 -> bank step 4, conflict-free reads
    __shared__ float Ps[512];
    __shared__ float css[8];
    int t = threadIdx.x;
    int r0 = blockIdx.x * 32;
    const float4* hg = (const float4*)(h + (size_t)r0 * 64);
    float4* As4 = (float4*)As;
    size_t totf4 = (size_t)N * 16;
#pragma unroll
    for (int i = 0; i < 2; i++) {
        int idx = t + i * 256;
        size_t gidx = (size_t)r0 * 16 + idx;
        float4 v = (gidx < totf4) ? hg[idx] : make_float4(0.f, 0.f, 0.f, 0.f);
        As4[(idx >> 4) * 17 + (idx & 15)] = v;
    }
    Ps[t] = P[t];
    Ps[t + 256] = P[t + 256];
    if (t < 8) css[t] = cs[t];
    __syncthreads();
    int row = t >> 3, o = t & 7;
    int rg = r0 + row;
    if (rg >= N) return;
    float acc = css[o];
#pragma unroll 8
    for (int k = 0; k < 64; k++) acc += As[row * 68 + k] * Ps[k * 8 + o];
    a_sd[(size_t)rg * 8 + o] = acc;
}

// ============================ edge exp scores -> CSR-ordered 16B records ============================
// rec[p] = { src, 0, ex(4 x f16) } with ex = exp(leaky_relu(a_s[src]+a_d[dst]+edge_attr@Qm))
__global__ void edge_ex_kernel(const int* __restrict__ esrc, const int* __restrict__ edst,
                               const float* __restrict__ edge_attr, const float* __restrict__ a_sd,
                               const float* __restrict__ Qm, const int* __restrict__ pos,
                               int4* __restrict__ rec, int E) {
    int e = blockIdx.x * 256 + threadIdx.x;
    if (e >= E) return;
    int src = esrc[e], dst = edst[e];
    F4 ea0, ea1, as, ad;
    ea0.v = ((const float4*)edge_attr)[(size_t)e * 2];
    ea1.v = ((const float4*)edge_attr)[(size_t)e * 2 + 1];
    as.v = ((const float4*)a_sd)[(size_t)src * 2];
    ad.v = ((const float4*)a_sd)[(size_t)dst * 2 + 1];
    f16x4 exh;
#pragma unroll
    for (int hh = 0; hh < 4; hh++) {
        float ae = ea0.a[0] * Qm[0 * 4 + hh] + ea0.a[1] * Qm[1 * 4 + hh]
                 + ea0.a[2] * Qm[2 * 4 + hh] + ea0.a[3] * Qm[3 * 4 + hh]
                 + ea1.a[0] * Qm[4 * 4 + hh] + ea1.a[1] * Qm[5 * 4 + hh]
                 + ea1.a[2] * Qm[6 * 4 + hh] + ea1.a[3] * Qm[7 * 4 + hh];
        float s = as.a[hh] + ad.a[hh] + ae;
        s = s > 0.f ? s : 0.2f * s;
        exh[hh] = (_Float16)__expf(s);
    }
    union { f16x4 h; int2 i; } u;
    u.h = exh;
    int4 r;
    r.x = src; r.y = 0; r.z = u.i.x; r.w = u.i.y;
    rec[pos[e]] = r;
}

// ============================ fused aggregation + projection (MFMA) ============================
// 16 nodes/block, 4 waves. Edge phase: lane = slot*16 + c4; each slot owns ONE node
// (row = wv*4+slot) and walks its CSR edges; 16 lanes x float4 cover the 64-ch h row.
// 4 independent gather chains per wave. LDS gets fp16 A rows (k = c*4+h); MFMA phase
// projects [16x256]@[256x64], wave wv owns cols wv*16..+15.
__global__ __launch_bounds__(256) void msg_proj_kernel(
        const int* __restrict__ row_ptr, const int4* __restrict__ rec,
        const float* __restrict__ h_in,
        const _Float16* __restrict__ Wt, const float* __restrict__ bpb,
        const float* __restrict__ bias, float* __restrict__ h_out, int N) {
    __shared__ __attribute__((aligned(16))) _Float16 Aagg[16][264];
    __shared__ __attribute__((aligned(16))) float sals[16][4];
    int t = threadIdx.x;
    int wv = t >> 6, lane = t & 63;
    int colg = wv * 16 + (lane & 15);
    int kb = (lane >> 4) * 8;

    // B fragments: lane holds n=lane&15, k = ks*32 + (lane>>4)*8 + j
    f16x8 bfrag[8];
    const _Float16* wtp = Wt + (size_t)colg * 256 + kb;
#pragma unroll
    for (int ks = 0; ks < 8; ks++) bfrag[ks] = *(const f16x8*)(wtp + ks * 32);
    float bpbc[4];
#pragma unroll
    for (int hh = 0; hh < 4; hh++) bpbc[hh] = bpb[hh * 64 + colg] * 0.25f;
    float bcol = bias[colg];

    // -------- edge phase --------
    int slot = lane >> 4;        // which node of this wave's 4
    int c4 = lane & 15;          // float4 channel chunk
    int row = wv * 4 + slot;     // 0..15 within tile
    int n = blockIdx.x * 16 + row;

    float4 A0 = {0.f,0.f,0.f,0.f}, A1 = A0, A2 = A0, A3 = A0;
    float d0 = 0.f, d1 = 0.f, d2 = 0.f, d3 = 0.f;
    if (n < N) {
        int p0 = row_ptr[n], p1 = row_ptr[n + 1];
        for (int p = p0; p < p1; p++) {
            int4 er = rec[p];
            union { int2 i; f16x4 h; } u;
            u.i = make_int2(er.z, er.w);
            float e0 = (float)u.h[0], e1 = (float)u.h[1], e2 = (float)u.h[2], e3 = (float)u.h[3];
            float4 hv = *(const float4*)(h_in + ((size_t)er.x << 6) + c4 * 4);
            A0.x = fmaf(e0, hv.x, A0.x); A0.y = fmaf(e0, hv.y, A0.y);
            A0.z = fmaf(e0, hv.z, A0.z); A0.w = fmaf(e0, hv.w, A0.w);
            A1.x = fmaf(e1, hv.x, A1.x); A1.y = fmaf(e1, hv.y, A1.y);
            A1.z = fmaf(e1, hv.z, A1.z); A1.w = fmaf(e1, hv.w, A1.w);
            A2.x = fmaf(e2, hv.x, A2.x); A2.y = fmaf(e2, hv.y, A2.y);
            A2.z = fmaf(e2, hv.z, A2.z); A2.w = fmaf(e2, hv.w, A2.w);
            A3.x = fmaf(e3, hv.x, A3.x); A3.y = fmaf(e3, hv.y, A3.y);
            A3.z = fmaf(e3, hv.z, A3.z); A3.w = fmaf(e3, hv.w, A3.w);
            d0 += e0; d1 += e1; d2 += e2; d3 += e3;
        }
    }
    float i0 = 1.f / (d0 + EPS_SM), i1 = 1.f / (d1 + EPS_SM);
    float i2 = 1.f / (d2 + EPS_SM), i3 = 1.f / (d3 + EPS_SM);
    // LDS layout k = c*4 + h; lane covers k = c4*16 .. c4*16+15
    f16x8 v0, v1;
    {
        const float* a0 = (const float*)&A0;
        const float* a1 = (const float*)&A1;
        const float* a2 = (const float*)&A2;
        const float* a3 = (const float*)&A3;
#pragma unroll
        for (int cc = 0; cc < 2; cc++) {
            v0[cc * 4 + 0] = (_Float16)(a0[cc] * i0);
            v0[cc * 4 + 1] = (_Float16)(a1[cc] * i1);
            v0[cc * 4 + 2] = (_Float16)(a2[cc] * i2);
            v0[cc * 4 + 3] = (_Float16)(a3[cc] * i3);
        }
#pragma unroll
        for (int cc = 0; cc < 2; cc++) {
            v1[cc * 4 + 0] = (_Float16)(a0[cc + 2] * i0);
            v1[cc * 4 + 1] = (_Float16)(a1[cc + 2] * i1);
            v1[cc * 4 + 2] = (_Float16)(a2[cc + 2] * i2);
            v1[cc * 4 + 3] = (_Float16)(a3[cc + 2] * i3);
        }
    }
    *(f16x8*)&Aagg[row][c4 * 16] = v0;
    *(f16x8*)&Aagg[row][c4 * 16 + 8] = v1;
    if (c4 == 0) {
        float4 sv;
        sv.x = d0 / (d0 + EPS_SM);
        sv.y = d1 / (d1 + EPS_SM);
        sv.z = d2 / (d2 + EPS_SM);
        sv.w = d3 / (d3 + EPS_SM);
        *(float4*)&sals[row][0] = sv;
    }
    __syncthreads();

    // -------- MFMA phase --------
    f32x4 acc = {0.f, 0.f, 0.f, 0.f};
    const _Float16* ap = &Aagg[lane & 15][kb];
#pragma unroll
    for (int ks = 0; ks < 8; ks++) {
        f16x8 af = *(const f16x8*)(ap + ks * 32);
        acc = __builtin_amdgcn_mfma_f32_16x16x32_f16(af, bfrag[ks], acc, 0, 0, 0);
    }
    int r0 = (lane >> 4) * 4;
    int nb0 = blockIdx.x * 16;
#pragma unroll
    for (int reg = 0; reg < 4; reg++) {
        int rr = r0 + reg;
        int nn = nb0 + rr;
        if (nn < N) {
            float v = acc[reg] + sals[rr][0] * bpbc[0] + sals[rr][1] * bpbc[1]
                    + sals[rr][2] * bpbc[2] + sals[rr][3] * bpbc[3] + bcol;
            size_t idx = ((size_t)nn << 6) + colg;
            float hv = h_in[idx];
            h_out[idx] = fmaxf(v, 0.f) + hv;
        }
    }
}

// ============================ pooling + FC head ============================
__global__ void pool_fc_kernel(const float* __restrict__ h, const int* __restrict__ gptr,
                               const float* __restrict__ fc1_w, const float* __restrict__ fc1_b,
                               const float* __restrict__ fc2_w, const float* __restrict__ fc2_b,
                               float* __restrict__ out, int G) {
    __shared__ float pool[4][64];
    int lane = threadIdx.x & 63, wv = threadIdx.x >> 6;
    int g = blockIdx.x * 4 + wv;
    float acc = 0.f;
    if (g < G) {
        int a = gptr[g], b = gptr[g + 1];
        for (int r = a; r < b; r++) acc += h[(size_t)r * 64 + lane];
    }
    pool[wv][lane] = acc;
    __syncthreads();
    float z1 = fc1_b[lane];
#pragma unroll 8
    for (int c = 0; c < 64; c++) z1 += pool[wv][c] * fc1_w[c * 64 + lane];
    z1 = fmaxf(z1, 0.f);
    float z2 = z1 * fc2_w[lane];
    z2 += __shfl_xor(z2, 1);
    z2 += __shfl_xor(z2, 2);
    z2 += __shfl_xor(z2, 4);
    z2 += __shfl_xor(z2, 8);
    z2 += __shfl_xor(z2, 16);
    z2 += __shfl_xor(z2, 32);
    if (g < G && lane == 0) out[g] = fmaxf(z2 + fc2_b[0], 0.f);
}

// ============================ host ============================
extern "C" void kernel_launch(void* const* d_in, const int* in_sizes, int n_in,
                              void* d_out, int out_size, void* d_ws, size_t ws_size,
                              hipStream_t stream) {
    const float* x         = (const float*)d_in[0];
    const int*   eindex    = (const int*)d_in[1];
    const float* edge_attr = (const float*)d_in[2];
    const int*   batch     = (const int*)d_in[3];
    const float* lin_w     = (const float*)d_in[4];
    const float* lin_b     = (const float*)d_in[5];
    const float* bn_gamma  = (const float*)d_in[6];
    const float* bn_beta   = (const float*)d_in[7];
    const float* conv_w    = (const float*)d_in[8];
    const float* conv_we   = (const float*)d_in[9];
    const float* att_src   = (const float*)d_in[10];
    const float* att_dst   = (const float*)d_in[11];
    const float* att_edge  = (const float*)d_in[12];
    const float* conv_bias = (const float*)d_in[13];
    const float* fc1_w     = (const float*)d_in[14];
    const float* fc1_b     = (const float*)d_in[15];
    const float* fc2_w     = (const float*)d_in[16];
    const float* fc2_b     = (const float*)d_in[17];
    float* out = (float*)d_out;

    int N = in_sizes[3];
    int E = in_sizes[1] / 2;
    int G = out_size;
    const int* esrc = eindex;
    const int* edst = eindex + E;

    char* wp = (char*)d_ws;
    auto carve = [&](size_t b) -> char* {
        char* p = wp;
        wp += (b + 511) & ~(size_t)511;
        return p;
    };
    float*     hb0    = (float*)carve((size_t)N * 64 * 4);      // 51.2 MB
    float*     hb1    = (float*)carve((size_t)N * 64 * 4);      // 51.2 MB
    float*     a_sd   = (float*)carve((size_t)N * 8 * 4);       //  6.4 MB
    int4*      rec    = (int4*)carve((size_t)E * 16);           //  6.4 MB
    int*       deg    = (int*)carve((size_t)N * 4);
    int*       row_ptr= (int*)carve((size_t)(N + 1) * 4);
    int*       cursor = (int*)carve((size_t)N * 4);
    int*       bsum   = (int*)carve(4096);
    int*       pos    = (int*)carve((size_t)E * 4);
    int*       gptr   = (int*)carve((size_t)(G + 1) * 4);
    float*     bpb    = (float*)carve(256 * 4);
    float*     P      = (float*)carve(512 * 4);
    float*     cs     = (float*)carve(8 * 4);
    float*     Qm     = (float*)carve(32 * 4);
    _Float16*  Wt     = (_Float16*)carve(64 * 256 * 2);
    float*     red    = (float*)carve(128 * 4);
    int nbS = (N + 511) / 512;
    float*     bnpart = (float*)carve((size_t)nbS * 128 * 4);

    int nb1 = (N + 255) / 256;

    // CSR + graph ranges (static across layers)
    zero_kernel<<<nb1, 256, 0, stream>>>(deg, N);
    hist_kernel<<<(E + 255) / 256, 256, 0, stream>>>(edst, deg, E);
    scan1_kernel<<<nb1, 256, 0, stream>>>(deg, row_ptr, bsum, N);
    scan2_kernel<<<1, 1024, 0, stream>>>(bsum, nb1);
    scan3_kernel<<<(N + 1 + 255) / 256, 256, 0, stream>>>(row_ptr, cursor, bsum, N, E);
    scatter_kernel<<<(E + 255) / 256, 256, 0, stream>>>(edst, cursor, pos, E);
    gptr_kernel<<<(G + 1 + 255) / 256, 256, 0, stream>>>(batch, gptr, N, G);

    // input projection
    proj_kernel<<<(N + 63) / 64, 256, 0, stream>>>(x, lin_w, lin_b, hb0, N);

    int cur = 0;
    float* hbuf[2] = {hb0, hb1};
    int mpGrid = (N + 15) / 16;

    for (int l = 0; l < 3; l++) {
        float* hc = hbuf[cur];
        float* hn = hbuf[cur ^ 1];
        bn_stats_kernel<<<nbS, 256, 0, stream>>>(hc, bnpart, N);
        bn_reduce_kernel<<<128, 256, 0, stream>>>(bnpart, nbS, red);
        fold2_kernel<<<67, 256, 0, stream>>>(red,
                                             bn_gamma + l * 64, bn_beta + l * 64,
                                             conv_w + (size_t)l * 64 * 256,
                                             conv_we + (size_t)l * 8 * 256,
                                             att_src + l * 256, att_dst + l * 256, att_edge + l * 256,
                                             Wt, bpb, P, cs, Qm, 1.f / (float)N);
        att_node_kernel<<<(N + 31) / 32, 256, 0, stream>>>(hc, P, cs, a_sd, N);
        edge_ex_kernel<<<(E + 255) / 256, 256, 0, stream>>>(esrc, edst, edge_attr, a_sd, Qm,
                                                            pos, rec, E);
        msg_proj_kernel<<<mpGrid, 256, 0, stream>>>(row_ptr, rec, hc, Wt, bpb,
                                                    conv_bias + l * 64, hn, N);
        cur ^= 1;
    }

    pool_fc_kernel<<<(G + 3) / 4, 256, 0, stream>>>(hbuf[cur], gptr, fc1_w, fc1_b, fc2_w, fc2_b,
                                                    out, G);
}